// Round 8
// baseline (422.165 us; speedup 1.0000x reference)
//
#include <hip/hip_runtime.h>

// Trilinear grid_pull, bound='zero', extrapolate=False.
// input: (B=2, C=2, 128^3) f32; grid: (B=2, 3, 128^3) f32 voxel coords.
//
// R7 evidence: p4=50us/batch (4 f4 taps/pt, transaction/latency bound,
// 0.66 trans/cyc/CU); pipeline overhead (p5 random-gather unpermute 55us,
// pos traffic, 10 launches) now ~= gather cost. This round:
//  - p4 scatter-stores results directly to out[s] (s carried in rec.w);
//    p5 + pos deleted (random loads -> fire-and-forget stores).
//  - batches merged: 16 bins, 4 launches total. ws ~103 MB (<120.6 proven).

#define NDIM  128
#define NV    (128 * 128 * 128)     // 2^21 voxels per (b,c) volume
#define NPTS  (2 * NV)              // 4,194,304 points
#define NBINS 16                    // (batch 2) x (x-slab 8), slab depth 16
#define CAP   270336                // 262144 mean + ~16 sigma
#define NBLK  4096                  // NPTS / 1024

typedef float f4 __attribute__((ext_vector_type(4)));
typedef float f2 __attribute__((ext_vector_type(2)));

// ---------------- P0: zero bin cursors ----------------
__global__ void p0_zero(int* __restrict__ cursor) {
    if (threadIdx.x < NBINS) cursor[threadIdx.x] = 0;
}

// ---------------- P2: repack (B,C,V) -> (B,V,C) ----------------
__global__ __launch_bounds__(256) void p2_repack(
    const float* __restrict__ input, float* __restrict__ pk)
{
    const int t  = blockIdx.x * blockDim.x + threadIdx.x;
    const int v4 = t << 2;
    const int b  = v4 >> 21;
    const int v  = v4 & (NV - 1);
    const float* base = input + (size_t)b * 2 * NV;
    const f4 a = __builtin_nontemporal_load(reinterpret_cast<const f4*>(base + v));
    const f4 c = __builtin_nontemporal_load(reinterpret_cast<const f4*>(base + NV + v));
    f4 w0, w1;
    w0.x = a.x; w0.y = c.x; w0.z = a.y; w0.w = c.y;
    w1.x = a.z; w1.y = c.z; w1.z = a.w; w1.w = c.w;
    float* o = pk + (size_t)b * 2 * NV + 2 * v;
    *reinterpret_cast<f4*>(o)     = w0;   // normal store: reused by p4
    *reinterpret_cast<f4*>(o + 4) = w1;
}

// ---------------- P3: scatter points into bins ----------------
__global__ __launch_bounds__(256) void p3_scatter(
    const float* __restrict__ grid,   // (B,3,NV)
    f4* __restrict__ rec,             // [NBINS*CAP] {x,y,z,bitcast(global s)}
    int* __restrict__ cursor)         // [NBINS]
{
    __shared__ int lcnt[NBINS];
    __shared__ int lbase[NBINS];
    const int t  = blockIdx.x * blockDim.x + threadIdx.x;
    const int s4 = t << 2;                 // global point index (first of 4)
    const int b  = s4 >> 21;
    const int s  = s4 & (NV - 1);

    if (threadIdx.x < NBINS) lcnt[threadIdx.x] = 0;
    __syncthreads();

    const float* gbase = grid + (size_t)b * 3 * NV;
    const f4 gx = __builtin_nontemporal_load(reinterpret_cast<const f4*>(gbase + s));
    const f4 gy = __builtin_nontemporal_load(reinterpret_cast<const f4*>(gbase + NV + s));
    const f4 gz = __builtin_nontemporal_load(reinterpret_cast<const f4*>(gbase + 2 * NV + s));

    int mybin[4], myrank[4];
#pragma unroll
    for (int k = 0; k < 4; ++k) {
        const int ix = (int)floorf(gx[k]);             // NaN -> 0
        mybin[k]  = (b << 3) + (min(max(ix, 0), NDIM - 1) >> 4);
        myrank[k] = atomicAdd(&lcnt[mybin[k]], 1);
    }
    __syncthreads();
    if (threadIdx.x < NBINS)
        lbase[threadIdx.x] = atomicAdd(&cursor[threadIdx.x], lcnt[threadIdx.x]);
    __syncthreads();

#pragma unroll
    for (int k = 0; k < 4; ++k) {
        const int d = mybin[k] * CAP + lbase[mybin[k]] + myrank[k];
        f4 r;
        r.x = gx[k]; r.y = gy[k]; r.z = gz[k];
        r.w = __int_as_float(s4 + k);      // global point index
        __builtin_nontemporal_store(r, &rec[d]);
    }
}

// ---------------- P4: slab-local gather + direct scatter-store ----------------
__global__ __launch_bounds__(256) void p4_gather(
    const float* __restrict__ pk,     // (B,V,C) interleaved
    const f4* __restrict__ rec,
    const int* __restrict__ cursor,
    float* __restrict__ out)          // (B,C,V)
{
    const int bid = blockIdx.x;
    // time-partition: bins 0..7 first (one per XCD via bid%8), then 8..15
    const int bin   = (bid < (NBLK / 2)) ? (bid & 7) : 8 + (bid & 7);
    const int chunk = (bid & (NBLK / 2 - 1)) >> 3;     // 0..255
    const int cnt   = cursor[bin];
    const int b     = bin >> 3;                        // batch (wave-uniform)
    const int seg   = bin * CAP;
    const float* pkb = pk  + (size_t)b * 2 * NV;
    float* outb      = out + (size_t)b * 2 * NV;

    for (int i = chunk * 1024 + (threadIdx.x << 2); i < cnt; i += 256 * 1024) {
        // phase A: 4 rec loads (dead lanes clamped to a valid slot)
        bool live[4];
        f4 r[4];
#pragma unroll
        for (int k = 0; k < 4; ++k) {
            live[k] = (i + k) < cnt;
            r[k] = rec[live[k] ? (seg + i + k) : seg];
        }
        // phase B: 16 f4 tap loads, all issued before the math
        f4 t00[4], t01[4], t10[4], t11[4];
        bool inb[4], interior[4];
        float wx[4], wy[4], wz[4];
        int ixa[4], iya[4], iza[4];
#pragma unroll
        for (int k = 0; k < 4; ++k) {
            const float x = r[k].x, y = r[k].y, z = r[k].z;
            const float fx = floorf(x), fy = floorf(y), fz = floorf(z);
            wx[k] = x - fx; wy[k] = y - fy; wz[k] = z - fz;
            const int ix = (int)fx, iy = (int)fy, iz = (int)fz;
            ixa[k] = ix; iya[k] = iy; iza[k] = iz;
            inb[k] = (x >= 0.0f) & (x <= (float)(NDIM - 1)) &
                     (y >= 0.0f) & (y <= (float)(NDIM - 1)) &
                     (z >= 0.0f) & (z <= (float)(NDIM - 1));
            interior[k] = inb[k] &
                          ((unsigned)ix < (unsigned)(NDIM - 1)) &
                          ((unsigned)iy < (unsigned)(NDIM - 1)) &
                          ((unsigned)iz < (unsigned)(NDIM - 1));
            const int base = interior[k] ? ((ix << 14) + (iy << 7) + iz) : 0;
            const f4* q = reinterpret_cast<const f4*>(pkb + 2 * base);
            t00[k] = q[0];          // (x  ,y  ): {c0[z],c1[z],c0[z+1],c1[z+1]}
            t01[k] = q[64];         // (x  ,y+1)
            t10[k] = q[8192];       // (x+1,y  )
            t11[k] = q[8256];       // (x+1,y+1)
        }
        // phase C: math + scatter-store to out[s]
#pragma unroll
        for (int k = 0; k < 4; ++k) {
            float acc0 = 0.0f, acc1 = 0.0f;
            const float wz0 = 1.0f - wz[k];
            if (interior[k]) {
                const float wx0 = 1.0f - wx[k], wy0 = 1.0f - wy[k];
                const float w00 = wx0 * wy0,   w01 = wx0 * wy[k];
                const float w10 = wx[k] * wy0, w11 = wx[k] * wy[k];
                const float z00a = fmaf(t00[k].z, wz[k], t00[k].x * wz0);
                const float z01a = fmaf(t01[k].z, wz[k], t01[k].x * wz0);
                const float z10a = fmaf(t10[k].z, wz[k], t10[k].x * wz0);
                const float z11a = fmaf(t11[k].z, wz[k], t11[k].x * wz0);
                acc0 = fmaf(z11a, w11, fmaf(z10a, w10, fmaf(z01a, w01, z00a * w00)));
                const float z00b = fmaf(t00[k].w, wz[k], t00[k].y * wz0);
                const float z01b = fmaf(t01[k].w, wz[k], t01[k].y * wz0);
                const float z10b = fmaf(t10[k].w, wz[k], t10[k].y * wz0);
                const float z11b = fmaf(t11[k].w, wz[k], t11[k].y * wz0);
                acc1 = fmaf(z11b, w11, fmaf(z10b, w10, fmaf(z01b, w01, z00b * w00)));
            } else if (inb[k]) {
                for (int dx = 0; dx < 2; ++dx) {
                    const int X = ixa[k] + dx;
                    if ((unsigned)X >= (unsigned)NDIM) continue;
                    const float wxd = dx ? wx[k] : 1.0f - wx[k];
                    for (int dy = 0; dy < 2; ++dy) {
                        const int Y = iya[k] + dy;
                        if ((unsigned)Y >= (unsigned)NDIM) continue;
                        const float wyd = dy ? wy[k] : 1.0f - wy[k];
                        for (int dz = 0; dz < 2; ++dz) {
                            const int Z = iza[k] + dz;
                            if ((unsigned)Z >= (unsigned)NDIM) continue;
                            const float w = wxd * wyd * (dz ? wz[k] : wz0);
                            const f2 v = *reinterpret_cast<const f2*>(
                                pkb + 2 * ((X << 14) + (Y << 7) + Z));
                            acc0 = fmaf(v.x, w, acc0);
                            acc1 = fmaf(v.y, w, acc1);
                        }
                    }
                }
            }
            if (live[k]) {
                const int sp = __float_as_int(r[k].w) & (NV - 1);  // spatial idx
                __builtin_nontemporal_store(acc0, outb + sp);
                __builtin_nontemporal_store(acc1, outb + NV + sp);
            }
        }
    }
}

// ================= fallback paths =================
__global__ __launch_bounds__(256) void grid_pull_packed_kernel(
    const float* __restrict__ pk,
    const float* __restrict__ grid,
    float* __restrict__ out)
{
    const int t  = blockIdx.x * blockDim.x + threadIdx.x;
    const int p4i = t << 2;
    const int b  = p4i >> 21;
    const int s  = p4i & (NV - 1);
    const float* gbase = grid + (size_t)b * 3 * NV;
    const f4 gx = *reinterpret_cast<const f4*>(gbase + s);
    const f4 gy = *reinterpret_cast<const f4*>(gbase + NV + s);
    const f4 gz = *reinterpret_cast<const f4*>(gbase + 2 * NV + s);
    const float* p = pk + (size_t)b * 2 * NV;
    f4 o0, o1;
#pragma unroll
    for (int k = 0; k < 4; ++k) {
        const float x = gx[k], y = gy[k], z = gz[k];
        const float fx = floorf(x), fy = floorf(y), fz = floorf(z);
        const float wx = x - fx, wy = y - fy, wz = z - fz;
        const int ix = (int)fx, iy = (int)fy, iz = (int)fz;
        const bool inb = (x >= 0.0f) & (x <= (float)(NDIM - 1)) &
                         (y >= 0.0f) & (y <= (float)(NDIM - 1)) &
                         (z >= 0.0f) & (z <= (float)(NDIM - 1));
        float acc0 = 0.0f, acc1 = 0.0f;
        if (inb) {
            for (int dx = 0; dx < 2; ++dx) {
                const int X = ix + dx;
                if ((unsigned)X >= (unsigned)NDIM) continue;
                const float wxd = dx ? wx : 1.0f - wx;
                for (int dy = 0; dy < 2; ++dy) {
                    const int Y = iy + dy;
                    if ((unsigned)Y >= (unsigned)NDIM) continue;
                    const float wyd = dy ? wy : 1.0f - wy;
                    for (int dz = 0; dz < 2; ++dz) {
                        const int Z = iz + dz;
                        if ((unsigned)Z >= (unsigned)NDIM) continue;
                        const float w = wxd * wyd * (dz ? wz : 1.0f - wz);
                        const f2 v = *reinterpret_cast<const f2*>(
                            p + (X << 15) + (Y << 8) + (Z << 1));
                        acc0 = fmaf(v.x, w, acc0);
                        acc1 = fmaf(v.y, w, acc1);
                    }
                }
            }
        }
        o0[k] = acc0; o1[k] = acc1;
    }
    float* obase = out + (size_t)b * 2 * NV + s;
    *reinterpret_cast<f4*>(obase)      = o0;
    *reinterpret_cast<f4*>(obase + NV) = o1;
}

__global__ __launch_bounds__(256) void grid_pull_direct_kernel(
    const float* __restrict__ input,
    const float* __restrict__ grid,
    float* __restrict__ out)
{
    const int t  = blockIdx.x * blockDim.x + threadIdx.x;
    const int p4i = t << 2;
    const int b  = p4i >> 21;
    const int s  = p4i & (NV - 1);
    const float* gbase = grid + (size_t)b * 3 * NV;
    const f4 gx = *reinterpret_cast<const f4*>(gbase + s);
    const f4 gy = *reinterpret_cast<const f4*>(gbase + NV + s);
    const f4 gz = *reinterpret_cast<const f4*>(gbase + 2 * NV + s);
    const float* in0 = input + (size_t)b * 2 * NV;
    const float* in1 = in0 + NV;
    f4 o0, o1;
#pragma unroll
    for (int k = 0; k < 4; ++k) {
        const float x = gx[k], y = gy[k], z = gz[k];
        const float fx = floorf(x), fy = floorf(y), fz = floorf(z);
        const float wx = x - fx, wy = y - fy, wz = z - fz;
        const int ix = (int)fx, iy = (int)fy, iz = (int)fz;
        const bool inb = (x >= 0.0f) & (x <= (float)(NDIM - 1)) &
                         (y >= 0.0f) & (y <= (float)(NDIM - 1)) &
                         (z >= 0.0f) & (z <= (float)(NDIM - 1));
        float acc0 = 0.0f, acc1 = 0.0f;
        if (inb) {
            for (int dx = 0; dx < 2; ++dx) {
                const int X = ix + dx;
                if ((unsigned)X >= (unsigned)NDIM) continue;
                const float wxd = dx ? wx : 1.0f - wx;
                for (int dy = 0; dy < 2; ++dy) {
                    const int Y = iy + dy;
                    if ((unsigned)Y >= (unsigned)NDIM) continue;
                    const float wyd = dy ? wy : 1.0f - wy;
                    for (int dz = 0; dz < 2; ++dz) {
                        const int Z = iz + dz;
                        if ((unsigned)Z >= (unsigned)NDIM) continue;
                        const float w = wxd * wyd * (dz ? wz : 1.0f - wz);
                        const int idx = (X << 14) + (Y << 7) + Z;
                        acc0 = fmaf(in0[idx], w, acc0);
                        acc1 = fmaf(in1[idx], w, acc1);
                    }
                }
            }
        }
        o0[k] = acc0; o1[k] = acc1;
    }
    float* obase = out + (size_t)b * 2 * NV + s;
    *reinterpret_cast<f4*>(obase)      = o0;
    *reinterpret_cast<f4*>(obase + NV) = o1;
}

extern "C" void kernel_launch(void* const* d_in, const int* in_sizes, int n_in,
                              void* d_out, int out_size, void* d_ws, size_t ws_size,
                              hipStream_t stream) {
    const float* input = (const float*)d_in[0];   // (2,2,128^3)
    const float* grid  = (const float*)d_in[1];   // (2,3,128^3)
    float* out         = (float*)d_out;           // (2,2,128^3)

    const size_t rec_bytes = (size_t)NBINS * CAP * sizeof(f4);   // 69.2 MB
    const size_t pk_bytes  = (size_t)NPTS * 2 * sizeof(float);   // 33.6 MB
    const size_t need_bin  = rec_bytes + pk_bytes + 256;         // ~102.8 MB
    const size_t need_pack = pk_bytes;                           // 33.6 MB

    const int block = 256;

    if (ws_size >= need_bin) {
        char* w = (char*)d_ws;
        f4*    rec    = (f4*)w;
        float* pk     = (float*)(w + rec_bytes);
        int*   cursor = (int*)(w + rec_bytes + pk_bytes);

        p0_zero<<<1, 64, 0, stream>>>(cursor);
        p2_repack<<<NBLK, block, 0, stream>>>(input, pk);
        p3_scatter<<<NBLK, block, 0, stream>>>(grid, rec, cursor);
        p4_gather<<<NBLK, block, 0, stream>>>(pk, rec, cursor, out);
    } else if (ws_size >= need_pack) {
        float* pk = (float*)d_ws;
        p2_repack<<<NBLK, block, 0, stream>>>(input, pk);
        grid_pull_packed_kernel<<<NBLK, block, 0, stream>>>(pk, grid, out);
    } else {
        grid_pull_direct_kernel<<<NBLK, block, 0, stream>>>(input, grid, out);
    }
}